// Round 1
// baseline (82.611 us; speedup 1.0000x reference)
//
#include <hip/hip_runtime.h>

#define OUTN 512
#define NCTL 64
#define BATCH 16

// One block per (b, u) output row.
// Phase 1: A[n][c] = sum_r Nu[u][r] * ctrl[b][uspan[u]-3+r][n][c]  (LDS, 1KB)
// Phase 2: per v: Sw[c] = sum_s Nv[v][s] * A[vspan[v]-3+s][c]; out = Sw.xyz / Sw.w
// Outputs staged in LDS, flushed as coalesced float4.
__global__ __launch_bounds__(256) void surfeval_kernel(
    const float* __restrict__ ctrl,   // (B,64,64,4)
    const int*   __restrict__ uspan,  // (512)
    const int*   __restrict__ vspan,  // (512)
    const float* __restrict__ Nu,     // (512,4)
    const float* __restrict__ Nv,     // (512,4)
    float*       __restrict__ out)    // (B,512,512,3)
{
    __shared__ float A[NCTL][4];        // 1 KB
    __shared__ float Sout[OUTN * 3];    // 6 KB

    const int u = blockIdx.x;
    const int b = blockIdx.y;
    const int t = threadIdx.x;

    // ---- Phase 1: contract over u-direction into A ----
    const int su = uspan[u];
    const float nu0 = Nu[u * 4 + 0];
    const float nu1 = Nu[u * 4 + 1];
    const float nu2 = Nu[u * 4 + 2];
    const float nu3 = Nu[u * 4 + 3];

    // thread t -> (n = t>>2, c = t&3); element t of each of 4 contiguous rows
    {
        const size_t rowbase = ((size_t)b * NCTL + (size_t)(su - 3)) * (NCTL * 4);
        const float* p = ctrl + rowbase + t;
        float a = nu0 * p[0]
                + nu1 * p[NCTL * 4]
                + nu2 * p[2 * NCTL * 4]
                + nu3 * p[3 * NCTL * 4];
        A[t >> 2][t & 3] = a;
    }
    __syncthreads();

    // ---- Phase 2: contract over v-direction, 2 v-points per thread ----
    #pragma unroll
    for (int vv = 0; vv < 2; ++vv) {
        const int v = t + vv * 256;
        const int sv = vspan[v];
        const float4 nv = ((const float4*)Nv)[v];
        const float4* Af = (const float4*)(&A[sv - 3][0]);
        const float4 s0 = Af[0];
        const float4 s1 = Af[1];
        const float4 s2 = Af[2];
        const float4 s3 = Af[3];
        const float sx = nv.x * s0.x + nv.y * s1.x + nv.z * s2.x + nv.w * s3.x;
        const float sy = nv.x * s0.y + nv.y * s1.y + nv.z * s2.y + nv.w * s3.y;
        const float sz = nv.x * s0.z + nv.y * s1.z + nv.z * s2.z + nv.w * s3.z;
        const float sw = nv.x * s0.w + nv.y * s1.w + nv.z * s2.w + nv.w * s3.w;
        const float inv = 1.0f / sw;
        Sout[v * 3 + 0] = sx * inv;
        Sout[v * 3 + 1] = sy * inv;
        Sout[v * 3 + 2] = sz * inv;
    }
    __syncthreads();

    // ---- Flush: 512*3 = 1536 floats = 384 float4, coalesced ----
    float4* og = (float4*)(out + ((size_t)b * OUTN + (size_t)u) * (OUTN * 3));
    const float4* sg = (const float4*)Sout;
    #pragma unroll
    for (int i = t; i < (OUTN * 3) / 4; i += 256) {
        og[i] = sg[i];
    }
}

extern "C" void kernel_launch(void* const* d_in, const int* in_sizes, int n_in,
                              void* d_out, int out_size, void* d_ws, size_t ws_size,
                              hipStream_t stream) {
    const float* ctrl  = (const float*)d_in[0];
    const int*   uspan = (const int*)d_in[1];
    const int*   vspan = (const int*)d_in[2];
    const float* Nu    = (const float*)d_in[3];
    const float* Nv    = (const float*)d_in[4];
    float* out = (float*)d_out;

    dim3 grid(OUTN, BATCH);
    surfeval_kernel<<<grid, 256, 0, stream>>>(ctrl, uspan, vspan, Nu, Nv, out);
}

// Round 2
// 80.747 us; speedup vs baseline: 1.0231x; 1.0231x over previous
//
#include <hip/hip_runtime.h>

#define OUTN 512
#define NCTL 64
#define BATCH 16

// One block per (b, u) output row, 256 threads, 2 v-points per thread.
// Phase 1: A[n][c] = sum_r Nu[u][r] * ctrl[b][uspan[u]-3+r][n][c]  (LDS, 1KB)
// Phase 2: per v: Sw[c] = sum_s Nv[v][s] * A[vspan[v]-3+s][c]; out = Sw.xyz/Sw.w
// Direct coalesced stores (wave writes 768B contiguous); single barrier.
__global__ __launch_bounds__(256) void surfeval_kernel(
    const float* __restrict__ ctrl,   // (B,64,64,4)
    const int*   __restrict__ uspan,  // (512)
    const int*   __restrict__ vspan,  // (512)
    const float* __restrict__ Nu,     // (512,4)
    const float* __restrict__ Nv,     // (512,4)
    float*       __restrict__ out)    // (B,512,512,3)
{
    __shared__ float A[NCTL][4];        // 1 KB

    const int u = blockIdx.x;
    const int b = blockIdx.y;
    const int t = threadIdx.x;

    // ---- Prefetch phase-2 inputs early (independent of phase 1) ----
    const int v0 = t;
    const int v1 = t + 256;
    const int sv0 = vspan[v0];
    const int sv1 = vspan[v1];
    const float4 nv0 = ((const float4*)Nv)[v0];
    const float4 nv1 = ((const float4*)Nv)[v1];

    // ---- Phase 1: contract over u-direction into A ----
    const int su = uspan[u];
    const float4 nu = ((const float4*)Nu)[u];
    {
        // thread t -> element t of each of 4 contiguous ctrl rows
        const float* p = ctrl + ((size_t)b * NCTL + (size_t)(su - 3)) * (NCTL * 4) + t;
        A[t >> 2][t & 3] = nu.x * p[0]
                         + nu.y * p[NCTL * 4]
                         + nu.z * p[2 * NCTL * 4]
                         + nu.w * p[3 * NCTL * 4];
    }
    __syncthreads();

    float* __restrict__ orow = out + ((size_t)b * OUTN + (size_t)u) * (OUTN * 3);

    // ---- Phase 2: v0 ----
    {
        const float4* Af = (const float4*)(&A[sv0 - 3][0]);
        const float4 s0 = Af[0], s1 = Af[1], s2 = Af[2], s3 = Af[3];
        const float sx = nv0.x * s0.x + nv0.y * s1.x + nv0.z * s2.x + nv0.w * s3.x;
        const float sy = nv0.x * s0.y + nv0.y * s1.y + nv0.z * s2.y + nv0.w * s3.y;
        const float sz = nv0.x * s0.z + nv0.y * s1.z + nv0.z * s2.z + nv0.w * s3.z;
        const float sw = nv0.x * s0.w + nv0.y * s1.w + nv0.z * s2.w + nv0.w * s3.w;
        const float inv = 1.0f / sw;
        orow[v0 * 3 + 0] = sx * inv;
        orow[v0 * 3 + 1] = sy * inv;
        orow[v0 * 3 + 2] = sz * inv;
    }
    // ---- Phase 2: v1 ----
    {
        const float4* Af = (const float4*)(&A[sv1 - 3][0]);
        const float4 s0 = Af[0], s1 = Af[1], s2 = Af[2], s3 = Af[3];
        const float sx = nv1.x * s0.x + nv1.y * s1.x + nv1.z * s2.x + nv1.w * s3.x;
        const float sy = nv1.x * s0.y + nv1.y * s1.y + nv1.z * s2.y + nv1.w * s3.y;
        const float sz = nv1.x * s0.z + nv1.y * s1.z + nv1.z * s2.z + nv1.w * s3.z;
        const float sw = nv1.x * s0.w + nv1.y * s1.w + nv1.z * s2.w + nv1.w * s3.w;
        const float inv = 1.0f / sw;
        orow[v1 * 3 + 0] = sx * inv;
        orow[v1 * 3 + 1] = sy * inv;
        orow[v1 * 3 + 2] = sz * inv;
    }
}

extern "C" void kernel_launch(void* const* d_in, const int* in_sizes, int n_in,
                              void* d_out, int out_size, void* d_ws, size_t ws_size,
                              hipStream_t stream) {
    const float* ctrl  = (const float*)d_in[0];
    const int*   uspan = (const int*)d_in[1];
    const int*   vspan = (const int*)d_in[2];
    const float* Nu    = (const float*)d_in[3];
    const float* Nv    = (const float*)d_in[4];
    float* out = (float*)d_out;

    dim3 grid(OUTN, BATCH);
    surfeval_kernel<<<grid, 256, 0, stream>>>(ctrl, uspan, vspan, Nu, Nv, out);
}